// Round 2
// baseline (6741.842 us; speedup 1.0000x reference)
//
#include <hip/hip_runtime.h>
#include <math.h>

#define Bn 2
#define Cn 192
#define Dn 48
#define Hn 48
#define Wn 48
#define C4 768
#define DHW (Dn*Hn*Wn)          // 110592 per batch
#define CDHW ((long)Cn*DHW)     // 21233664 per batch

__device__ inline float bf2f(unsigned short u) {
    union { float f; unsigned int i; } v; v.i = ((unsigned int)u) << 16; return v.f;
}
__device__ inline unsigned short f2bf(float f) {
    union { float f; unsigned int i; } v; v.f = f;
    unsigned int r = v.i + 0x7FFFu + ((v.i >> 16) & 1u);   // RNE
    return (unsigned short)(r >> 16);
}

// ---------------- depthwise conv 7x7x7, per-batch NCDHW -> NCDHW ----------------
__global__ __launch_bounds__(256)
void conv_dw(const float* __restrict__ x, const float* __restrict__ cw,
             const float* __restrict__ cb, float* __restrict__ yc)
{
    __shared__ float wl[343];
    long idx0 = (long)blockIdx.x * 256;
    int c = (int)(idx0 / DHW);            // uniform per block: 256 | DHW, b local = 0
    for (int i = threadIdx.x; i < 343; i += 256) wl[i] = cw[i * Cn + c];
    __syncthreads();

    long idx = idx0 + threadIdx.x;
    int w = (int)(idx % Wn); long t = idx / Wn;
    int h = (int)(t % Hn); t /= Hn;
    int d = (int)(t % Dn); t /= Dn;       // t = c
    const float* xb = x + t * (long)DHW;

    float sum = cb[c];
    int kd0 = max(0, 3 - d), kd1 = min(6, 50 - d);
    int kh0 = max(0, 3 - h), kh1 = min(6, 50 - h);
    int kw0 = max(0, 3 - w), kw1 = min(6, 50 - w);
    for (int kd = kd0; kd <= kd1; ++kd) {
        const float* xd = xb + (d + kd - 3) * (Hn * Wn);
        for (int kh = kh0; kh <= kh1; ++kh) {
            const float* xr = xd + (h + kh - 3) * Wn + (w - 3);
            const float* wr = wl + (kd * 7 + kh) * 7;
            for (int kw = kw0; kw <= kw1; ++kw)
                sum = fmaf(xr[kw], wr[kw], sum);
        }
    }
    yc[idx] = sum;
}

// ---------------- LayerNorm over C, per-batch NCDHW -> NDHWC (bf16 out) ----------------
__global__ __launch_bounds__(256)
void ln_kernel(const float* __restrict__ yc, const float* __restrict__ g,
               const float* __restrict__ lb, unsigned short* __restrict__ y1)
{
    __shared__ float tile[Cn * Wn];       // 36 KB
    __shared__ float mu_s[Wn], rs_s[Wn];
    int dh = blockIdx.x;                  // d*Hn + h
    long rowbase = (long)dh * Wn;
    for (int l = threadIdx.x; l < Cn * Wn; l += 256) {
        int c = l / Wn, w = l % Wn;
        tile[l] = yc[rowbase + (long)c * DHW + w];
    }
    __syncthreads();
    if (threadIdx.x < Wn) {
        int w = threadIdx.x;
        float s = 0.f;
        for (int c = 0; c < Cn; ++c) s += tile[c * Wn + w];
        float mu = s * (1.0f / Cn);
        float v = 0.f;
        for (int c = 0; c < Cn; ++c) { float dd = tile[c * Wn + w] - mu; v = fmaf(dd, dd, v); }
        mu_s[w] = mu;
        rs_s[w] = rsqrtf(v * (1.0f / Cn) + 1e-6f);
    }
    __syncthreads();
    long obase = (long)dh * Wn * Cn;
    for (int l = threadIdx.x; l < Cn * Wn; l += 256) {
        int w = l / Cn, c = l % Cn;
        float val = (tile[c * Wn + w] - mu_s[w]) * rs_s[w] * g[c] + lb[c];
        y1[obase + l] = f2bf(val);
    }
}

// ---------------- GEMM up: [DHW,192]bf16 @ [192,768]f32 + b1, exact GELU -> bf16 ----------------
__global__ __launch_bounds__(256)
void gemm_up(const unsigned short* __restrict__ A, const float* __restrict__ W1,
             const float* __restrict__ bias, unsigned short* __restrict__ Y2)
{
    __shared__ float As[16][68];
    __shared__ float Bs[16][68];
    int tid = threadIdx.x;
    int tx = tid & 15, ty = tid >> 4;
    long m0 = (long)blockIdx.x * 64;
    int n0 = blockIdx.y * 64;
    float acc[4][4] = {{0.f}};
    int lrow = tid >> 2, lk = (tid & 3) * 4;
    int brow = tid >> 4, bcol = (tid & 15) * 4;

    for (int k0 = 0; k0 < Cn; k0 += 16) {
        ushort4 av = *(const ushort4*)(A + (m0 + lrow) * Cn + k0 + lk);
        As[lk + 0][lrow] = bf2f(av.x); As[lk + 1][lrow] = bf2f(av.y);
        As[lk + 2][lrow] = bf2f(av.z); As[lk + 3][lrow] = bf2f(av.w);
        *(float4*)&Bs[brow][bcol] = *(const float4*)(W1 + (long)(k0 + brow) * C4 + n0 + bcol);
        __syncthreads();
#pragma unroll
        for (int k = 0; k < 16; ++k) {
            float a[4], b[4];
            *(float4*)a = *(const float4*)&As[k][ty * 4];
            *(float4*)b = *(const float4*)&Bs[k][tx * 4];
#pragma unroll
            for (int i = 0; i < 4; ++i)
#pragma unroll
                for (int j = 0; j < 4; ++j)
                    acc[i][j] = fmaf(a[i], b[j], acc[i][j]);
        }
        __syncthreads();
    }
#pragma unroll
    for (int i = 0; i < 4; ++i) {
        long m = m0 + ty * 4 + i;
        ushort4 o;
#pragma unroll
        for (int j = 0; j < 4; ++j) {
            float v = acc[i][j] + bias[n0 + tx * 4 + j];
            v = 0.5f * v * (1.0f + erff(v * 0.70710678118654752f));
            ((unsigned short*)&o)[j] = f2bf(v);
        }
        *(ushort4*)(Y2 + m * C4 + n0 + tx * 4) = o;
    }
}

// ---------------- GRN stats: per-block partial sums of squares (bf16 in) ----------------
__global__ __launch_bounds__(256)
void grn_stats(const unsigned short* __restrict__ Y2, float* __restrict__ partial)
{
    long m0 = (long)blockIdx.x * 128;
    float s0 = 0.f, s1 = 0.f, s2 = 0.f;
    for (int r = 0; r < 128; ++r) {
        const unsigned short* row = Y2 + (m0 + r) * C4;
        float v0 = bf2f(row[threadIdx.x]);       s0 = fmaf(v0, v0, s0);
        float v1 = bf2f(row[threadIdx.x + 256]); s1 = fmaf(v1, v1, s1);
        float v2 = bf2f(row[threadIdx.x + 512]); s2 = fmaf(v2, v2, s2);
    }
    float* p = partial + (long)blockIdx.x * C4;
    p[threadIdx.x] = s0; p[threadIdx.x + 256] = s1; p[threadIdx.x + 512] = s2;
}

// ---------------- GRN reduce: 864 partials -> gx2[n], n in [0,768) ----------------
__global__ __launch_bounds__(256)
void grn_reduce(const float* __restrict__ partial, float* __restrict__ gx2)
{
    int n = blockIdx.x;
    const float* p = partial + n;
    float s = 0.f;
    for (int r = threadIdx.x; r < 864; r += 256) s += p[(long)r * C4];
    __shared__ float red[256];
    red[threadIdx.x] = s; __syncthreads();
    for (int st = 128; st > 0; st >>= 1) {
        if (threadIdx.x < st) red[threadIdx.x] += red[threadIdx.x + st];
        __syncthreads();
    }
    if (threadIdx.x == 0) gx2[n] = red[0];
}

// ---------------- GRN scale: snx[n] = 1 + gamma[n]*nx ----------------
__global__ __launch_bounds__(256)
void grn_snx(const float* __restrict__ gx2, const float* __restrict__ gamma,
             float* __restrict__ snx)
{
    __shared__ float red[256];
    float gx[3]; float s = 0.f;
#pragma unroll
    for (int i = 0; i < 3; ++i) {
        int n = threadIdx.x + i * 256;
        gx[i] = sqrtf(gx2[n]);
        s += gx[i];
    }
    red[threadIdx.x] = s; __syncthreads();
    for (int st = 128; st > 0; st >>= 1) {
        if (threadIdx.x < st) red[threadIdx.x] += red[threadIdx.x + st];
        __syncthreads();
    }
    float inv = 1.0f / (red[0] * (1.0f / C4) + 1e-6f);
#pragma unroll
    for (int i = 0; i < 3; ++i) {
        int n = threadIdx.x + i * 256;
        snx[n] = 1.0f + gamma[n] * gx[i] * inv;
    }
}

// ---------------- effective down-bias: beff = b2 + beta @ W2 ----------------
__global__ __launch_bounds__(192)
void bias_eff_k(const float* __restrict__ beta, const float* __restrict__ W2,
                const float* __restrict__ b2, float* __restrict__ beff)
{
    int j = threadIdx.x;
    float s = b2[j];
    for (int k = 0; k < C4; ++k) s = fmaf(beta[k], W2[k * Cn + j], s);
    beff[j] = s;
}

// ---------------- GEMM down + residual, per-batch NDHWC -> NCDHW ----------------
__global__ __launch_bounds__(256)
void gemm_down(const unsigned short* __restrict__ Y2, const float* __restrict__ W2,
               const float* __restrict__ snx, const float* __restrict__ beff,
               const float* __restrict__ x, float* __restrict__ out)
{
    __shared__ float As[16][68];
    __shared__ float Bs[16][68];
    int tid = threadIdx.x;
    int tx = tid & 15, ty = tid >> 4;
    long m0 = (long)blockIdx.x * 64;
    int n0 = blockIdx.y * 64;
    float acc[4][4] = {{0.f}};
    int lrow = tid >> 2, lk = (tid & 3) * 4;
    int brow = tid >> 4, bcol = (tid & 15) * 4;

    for (int k0 = 0; k0 < C4; k0 += 16) {
        ushort4 av = *(const ushort4*)(Y2 + (m0 + lrow) * C4 + k0 + lk);
        float4 sv = *(const float4*)(snx + k0 + lk);
        As[lk + 0][lrow] = bf2f(av.x) * sv.x; As[lk + 1][lrow] = bf2f(av.y) * sv.y;
        As[lk + 2][lrow] = bf2f(av.z) * sv.z; As[lk + 3][lrow] = bf2f(av.w) * sv.w;
        *(float4*)&Bs[brow][bcol] = *(const float4*)(W2 + (long)(k0 + brow) * Cn + n0 + bcol);
        __syncthreads();
#pragma unroll
        for (int k = 0; k < 16; ++k) {
            float a[4], bb[4];
            *(float4*)a = *(const float4*)&As[k][ty * 4];
            *(float4*)bb = *(const float4*)&Bs[k][tx * 4];
#pragma unroll
            for (int i = 0; i < 4; ++i)
#pragma unroll
                for (int j = 0; j < 4; ++j)
                    acc[i][j] = fmaf(a[i], bb[j], acc[i][j]);
        }
        __syncthreads();
    }
#pragma unroll
    for (int j = 0; j < 4; ++j) {
        int cch = n0 + tx * 4 + j;
        float be = beff[cch];
        const float* xp = x + (long)cch * DHW + m0;
        float* op = out + (long)cch * DHW + m0;
#pragma unroll
        for (int i = 0; i < 4; ++i) {
            int sr = ty * 4 + i;
            op[sr] = acc[i][j] + be + xp[sr];
        }
    }
}

extern "C" void kernel_launch(void* const* d_in, const int* in_sizes, int n_in,
                              void* d_out, int out_size, void* d_ws, size_t ws_size,
                              hipStream_t stream) {
    const float* x      = (const float*)d_in[0];
    const float* conv_w = (const float*)d_in[1];
    const float* conv_b = (const float*)d_in[2];
    const float* ln_g   = (const float*)d_in[3];
    const float* ln_b   = (const float*)d_in[4];
    const float* w1     = (const float*)d_in[5];
    const float* b1     = (const float*)d_in[6];
    const float* gg     = (const float*)d_in[7];
    const float* gb     = (const float*)d_in[8];
    const float* w2     = (const float*)d_in[9];
    const float* b2     = (const float*)d_in[10];
    float* out = (float*)d_out;
    char* ws = (char*)d_ws;

    // per-batch workspace, ~216 MB total:
    //   y2  bf16 [DHW][768] = 169,869,312 B  (offset 0; overlaps yc)
    //   yc  f32  [192][DHW] =  84,934,656 B  (offset 0, dead before y2 written)
    //   y1  bf16 [DHW][192] =  42,467,328 B
    //   partial f32 [864][768] = 2,654,208 B;  gx2/snx/beff small
    unsigned short* y2 = (unsigned short*)(ws);
    float*          yc = (float*)(ws);
    unsigned short* y1 = (unsigned short*)(ws + 169869312L);
    float*     partial = (float*)(ws + 169869312L + 42467328L);
    float*         gx2 = partial + 864L * C4;
    float*         snx = gx2 + C4;
    float*        beff = snx + C4;

    bias_eff_k<<<1, 192, 0, stream>>>(gb, w2, b2, beff);

    for (int b = 0; b < Bn; ++b) {
        const float* xb = x + (size_t)b * CDHW;
        float* outb = out + (size_t)b * CDHW;
        conv_dw<<<(int)(CDHW / 256), 256, 0, stream>>>(xb, conv_w, conv_b, yc);
        ln_kernel<<<Dn * Hn, 256, 0, stream>>>(yc, ln_g, ln_b, y1);
        dim3 gu(DHW / 64, C4 / 64);
        gemm_up<<<gu, 256, 0, stream>>>(y1, w1, b1, y2);
        grn_stats<<<DHW / 128, 256, 0, stream>>>(y2, partial);
        grn_reduce<<<C4, 256, 0, stream>>>(partial, gx2);
        grn_snx<<<1, 256, 0, stream>>>(gx2, gg, snx);
        dim3 gd(DHW / 64, Cn / 64);
        gemm_down<<<gd, 256, 0, stream>>>(y2, w2, snx, beff, xb, outb);
    }
}

// Round 3
// 2731.605 us; speedup vs baseline: 2.4681x; 2.4681x over previous
//
#include <hip/hip_runtime.h>
#include <math.h>

#define Bn 2
#define Cn 192
#define Dn 48
#define Hn 48
#define Wn 48
#define C4 768
#define DHW (Dn*Hn*Wn)          // 110592 per batch
#define CDHW ((long)Cn*DHW)     // 21233664 per batch

__device__ inline float bf2f(unsigned short u) {
    union { float f; unsigned int i; } v; v.i = ((unsigned int)u) << 16; return v.f;
}
__device__ inline unsigned short f2bf(float f) {
    union { float f; unsigned int i; } v; v.f = f;
    unsigned int r = v.i + 0x7FFFu + ((v.i >> 16) & 1u);   // RNE
    return (unsigned short)(r >> 16);
}

// ---------------- depthwise conv 7x7x7, LDS-tiled, per-batch NCDHW -> NCDHW ----
// block: 128 threads, one channel, 8(d)x16(h)x16(w) output tile.
// thread: 2(d)x8(w) register tile at one h.
#define TD 8
#define TH 16
#define TW 16
#define HD (TD+6)     // 14
#define HH (TH+6)     // 22
#define HW (TW+6)     // 22
#define HWP 23        // padded w stride (odd -> bank spread)
#define HALO (HD*HH*HW)   // 6776 loads

__global__ __launch_bounds__(128)
void conv_dw(const float* __restrict__ x, const float* __restrict__ cw,
             const float* __restrict__ cb, float* __restrict__ yc)
{
    __shared__ float xt[HD][HH][HWP];     // 28,336 B
    __shared__ float wl[343];
    int c = blockIdx.y;
    int s = blockIdx.x;                   // 54 spatial tiles: 6(d) x 3(h) x 3(w)
    int wt = s % 3, ht = (s / 3) % 3, dt = s / 9;
    int d0 = dt * TD, h0 = ht * TH, w0 = wt * TW;
    int tid = threadIdx.x;

    for (int i = tid; i < 343; i += 128) wl[i] = cw[i * Cn + c];

    const float* xb = x + (long)c * DHW;
    for (int i = tid; i < HALO; i += 128) {
        int dd = i / (HH * HW);
        int r  = i % (HH * HW);
        int hh = r / HW, ww = r % HW;
        int gd = d0 - 3 + dd, gh = h0 - 3 + hh, gw = w0 - 3 + ww;
        bool ok = (unsigned)gd < 48u && (unsigned)gh < 48u && (unsigned)gw < 48u;
        xt[dd][hh][ww] = ok ? xb[(gd * 48 + gh) * 48 + gw] : 0.0f;
    }
    __syncthreads();

    int wg = tid & 1;                     // w half (8 outputs)
    int hh = (tid >> 1) & 15;             // output h within tile
    int dp = tid >> 5;                    // d pair index [0,4)
    float bias = cb[c];
    float acc[2][8];
#pragma unroll
    for (int t = 0; t < 2; ++t)
#pragma unroll
        for (int i = 0; i < 8; ++i) acc[t][i] = bias;

    for (int kh = 0; kh < 7; ++kh) {
        int hin = hh + kh;
#pragma unroll
        for (int rr = 0; rr < 8; ++rr) {
            int din = dp * 2 + rr;
            float xr[14];
#pragma unroll
            for (int j = 0; j < 14; ++j) xr[j] = xt[din][hin][wg * 8 + j];
#pragma unroll
            for (int t = 0; t < 2; ++t) {
                int kd = rr - t;
                if (kd < 0 || kd > 6) continue;
                const float* wr = wl + (kd * 7 + kh) * 7;
#pragma unroll
                for (int kw = 0; kw < 7; ++kw) {
                    float wv = wr[kw];
#pragma unroll
                    for (int i = 0; i < 8; ++i)
                        acc[t][i] = fmaf(xr[kw + i], wv, acc[t][i]);
                }
            }
        }
    }

    float* yb = yc + (long)c * DHW;
#pragma unroll
    for (int t = 0; t < 2; ++t) {
        int dout = d0 + dp * 2 + t;
        float* op = yb + (dout * 48 + h0 + hh) * 48 + w0 + wg * 8;
        *(float4*)op       = *(float4*)&acc[t][0];
        *(float4*)(op + 4) = *(float4*)&acc[t][4];
    }
}

// ---------------- LayerNorm over C, per-batch NCDHW -> NDHWC (bf16 out) ----------------
__global__ __launch_bounds__(256)
void ln_kernel(const float* __restrict__ yc, const float* __restrict__ g,
               const float* __restrict__ lb, unsigned short* __restrict__ y1)
{
    __shared__ float tile[Cn * Wn];       // 36 KB
    __shared__ float mu_s[Wn], rs_s[Wn];
    int dh = blockIdx.x;                  // d*Hn + h
    long rowbase = (long)dh * Wn;
    for (int l = threadIdx.x; l < Cn * Wn; l += 256) {
        int c = l / Wn, w = l % Wn;
        tile[l] = yc[rowbase + (long)c * DHW + w];
    }
    __syncthreads();
    if (threadIdx.x < Wn) {
        int w = threadIdx.x;
        float s = 0.f;
        for (int c = 0; c < Cn; ++c) s += tile[c * Wn + w];
        float mu = s * (1.0f / Cn);
        float v = 0.f;
        for (int c = 0; c < Cn; ++c) { float dd = tile[c * Wn + w] - mu; v = fmaf(dd, dd, v); }
        mu_s[w] = mu;
        rs_s[w] = rsqrtf(v * (1.0f / Cn) + 1e-6f);
    }
    __syncthreads();
    long obase = (long)dh * Wn * Cn;
    for (int l = threadIdx.x; l < Cn * Wn; l += 256) {
        int w = l / Cn, c = l % Cn;
        float val = (tile[c * Wn + w] - mu_s[w]) * rs_s[w] * g[c] + lb[c];
        y1[obase + l] = f2bf(val);
    }
}

// ---------------- GEMM up: [DHW,192]bf16 @ [192,768]f32 + b1, exact GELU -> bf16 ----------------
__global__ __launch_bounds__(256)
void gemm_up(const unsigned short* __restrict__ A, const float* __restrict__ W1,
             const float* __restrict__ bias, unsigned short* __restrict__ Y2)
{
    __shared__ float As[16][68];
    __shared__ float Bs[16][68];
    int tid = threadIdx.x;
    int tx = tid & 15, ty = tid >> 4;
    long m0 = (long)blockIdx.x * 64;
    int n0 = blockIdx.y * 64;
    float acc[4][4] = {{0.f}};
    int lrow = tid >> 2, lk = (tid & 3) * 4;
    int brow = tid >> 4, bcol = (tid & 15) * 4;

    for (int k0 = 0; k0 < Cn; k0 += 16) {
        ushort4 av = *(const ushort4*)(A + (m0 + lrow) * Cn + k0 + lk);
        As[lk + 0][lrow] = bf2f(av.x); As[lk + 1][lrow] = bf2f(av.y);
        As[lk + 2][lrow] = bf2f(av.z); As[lk + 3][lrow] = bf2f(av.w);
        *(float4*)&Bs[brow][bcol] = *(const float4*)(W1 + (long)(k0 + brow) * C4 + n0 + bcol);
        __syncthreads();
#pragma unroll
        for (int k = 0; k < 16; ++k) {
            float a[4], b[4];
            *(float4*)a = *(const float4*)&As[k][ty * 4];
            *(float4*)b = *(const float4*)&Bs[k][tx * 4];
#pragma unroll
            for (int i = 0; i < 4; ++i)
#pragma unroll
                for (int j = 0; j < 4; ++j)
                    acc[i][j] = fmaf(a[i], b[j], acc[i][j]);
        }
        __syncthreads();
    }
#pragma unroll
    for (int i = 0; i < 4; ++i) {
        long m = m0 + ty * 4 + i;
        ushort4 o;
#pragma unroll
        for (int j = 0; j < 4; ++j) {
            float v = acc[i][j] + bias[n0 + tx * 4 + j];
            v = 0.5f * v * (1.0f + erff(v * 0.70710678118654752f));
            ((unsigned short*)&o)[j] = f2bf(v);
        }
        *(ushort4*)(Y2 + m * C4 + n0 + tx * 4) = o;
    }
}

// ---------------- GRN stats: per-block partial sums of squares (bf16 in) ----------------
__global__ __launch_bounds__(256)
void grn_stats(const unsigned short* __restrict__ Y2, float* __restrict__ partial)
{
    long m0 = (long)blockIdx.x * 128;
    float s0 = 0.f, s1 = 0.f, s2 = 0.f;
    for (int r = 0; r < 128; ++r) {
        const unsigned short* row = Y2 + (m0 + r) * C4;
        float v0 = bf2f(row[threadIdx.x]);       s0 = fmaf(v0, v0, s0);
        float v1 = bf2f(row[threadIdx.x + 256]); s1 = fmaf(v1, v1, s1);
        float v2 = bf2f(row[threadIdx.x + 512]); s2 = fmaf(v2, v2, s2);
    }
    float* p = partial + (long)blockIdx.x * C4;
    p[threadIdx.x] = s0; p[threadIdx.x + 256] = s1; p[threadIdx.x + 512] = s2;
}

// ---------------- GRN reduce: 864 partials -> gx2[n], n in [0,768) ----------------
__global__ __launch_bounds__(256)
void grn_reduce(const float* __restrict__ partial, float* __restrict__ gx2)
{
    int n = blockIdx.x;
    const float* p = partial + n;
    float s = 0.f;
    for (int r = threadIdx.x; r < 864; r += 256) s += p[(long)r * C4];
    __shared__ float red[256];
    red[threadIdx.x] = s; __syncthreads();
    for (int st = 128; st > 0; st >>= 1) {
        if (threadIdx.x < st) red[threadIdx.x] += red[threadIdx.x + st];
        __syncthreads();
    }
    if (threadIdx.x == 0) gx2[n] = red[0];
}

// ---------------- GRN scale: snx[n] = 1 + gamma[n]*nx ----------------
__global__ __launch_bounds__(256)
void grn_snx(const float* __restrict__ gx2, const float* __restrict__ gamma,
             float* __restrict__ snx)
{
    __shared__ float red[256];
    float gx[3]; float s = 0.f;
#pragma unroll
    for (int i = 0; i < 3; ++i) {
        int n = threadIdx.x + i * 256;
        gx[i] = sqrtf(gx2[n]);
        s += gx[i];
    }
    red[threadIdx.x] = s; __syncthreads();
    for (int st = 128; st > 0; st >>= 1) {
        if (threadIdx.x < st) red[threadIdx.x] += red[threadIdx.x + st];
        __syncthreads();
    }
    float inv = 1.0f / (red[0] * (1.0f / C4) + 1e-6f);
#pragma unroll
    for (int i = 0; i < 3; ++i) {
        int n = threadIdx.x + i * 256;
        snx[n] = 1.0f + gamma[n] * gx[i] * inv;
    }
}

// ---------------- effective down-bias: beff = b2 + beta @ W2 ----------------
__global__ __launch_bounds__(192)
void bias_eff_k(const float* __restrict__ beta, const float* __restrict__ W2,
                const float* __restrict__ b2, float* __restrict__ beff)
{
    int j = threadIdx.x;
    float s = b2[j];
    for (int k = 0; k < C4; ++k) s = fmaf(beta[k], W2[k * Cn + j], s);
    beff[j] = s;
}

// ---------------- GEMM down + residual, per-batch NDHWC -> NCDHW ----------------
__global__ __launch_bounds__(256)
void gemm_down(const unsigned short* __restrict__ Y2, const float* __restrict__ W2,
               const float* __restrict__ snx, const float* __restrict__ beff,
               const float* __restrict__ x, float* __restrict__ out)
{
    __shared__ float As[16][68];
    __shared__ float Bs[16][68];
    int tid = threadIdx.x;
    int tx = tid & 15, ty = tid >> 4;
    long m0 = (long)blockIdx.x * 64;
    int n0 = blockIdx.y * 64;
    float acc[4][4] = {{0.f}};
    int lrow = tid >> 2, lk = (tid & 3) * 4;
    int brow = tid >> 4, bcol = (tid & 15) * 4;

    for (int k0 = 0; k0 < C4; k0 += 16) {
        ushort4 av = *(const ushort4*)(Y2 + (m0 + lrow) * C4 + k0 + lk);
        float4 sv = *(const float4*)(snx + k0 + lk);
        As[lk + 0][lrow] = bf2f(av.x) * sv.x; As[lk + 1][lrow] = bf2f(av.y) * sv.y;
        As[lk + 2][lrow] = bf2f(av.z) * sv.z; As[lk + 3][lrow] = bf2f(av.w) * sv.w;
        *(float4*)&Bs[brow][bcol] = *(const float4*)(W2 + (long)(k0 + brow) * Cn + n0 + bcol);
        __syncthreads();
#pragma unroll
        for (int k = 0; k < 16; ++k) {
            float a[4], bb[4];
            *(float4*)a = *(const float4*)&As[k][ty * 4];
            *(float4*)bb = *(const float4*)&Bs[k][tx * 4];
#pragma unroll
            for (int i = 0; i < 4; ++i)
#pragma unroll
                for (int j = 0; j < 4; ++j)
                    acc[i][j] = fmaf(a[i], bb[j], acc[i][j]);
        }
        __syncthreads();
    }
#pragma unroll
    for (int j = 0; j < 4; ++j) {
        int cch = n0 + tx * 4 + j;
        float be = beff[cch];
        const float* xp = x + (long)cch * DHW + m0;
        float* op = out + (long)cch * DHW + m0;
#pragma unroll
        for (int i = 0; i < 4; ++i) {
            int sr = ty * 4 + i;
            op[sr] = acc[i][j] + be + xp[sr];
        }
    }
}

extern "C" void kernel_launch(void* const* d_in, const int* in_sizes, int n_in,
                              void* d_out, int out_size, void* d_ws, size_t ws_size,
                              hipStream_t stream) {
    const float* x      = (const float*)d_in[0];
    const float* conv_w = (const float*)d_in[1];
    const float* conv_b = (const float*)d_in[2];
    const float* ln_g   = (const float*)d_in[3];
    const float* ln_b   = (const float*)d_in[4];
    const float* w1     = (const float*)d_in[5];
    const float* b1     = (const float*)d_in[6];
    const float* gg     = (const float*)d_in[7];
    const float* gb     = (const float*)d_in[8];
    const float* w2     = (const float*)d_in[9];
    const float* b2     = (const float*)d_in[10];
    float* out = (float*)d_out;
    char* ws = (char*)d_ws;

    // per-batch workspace, ~216 MB total:
    //   y2  bf16 [DHW][768] = 169,869,312 B  (offset 0; overlaps yc)
    //   yc  f32  [192][DHW] =  84,934,656 B  (offset 0, dead before y2 written)
    //   y1  bf16 [DHW][192] =  42,467,328 B
    //   partial f32 [864][768] = 2,654,208 B;  gx2/snx/beff small
    unsigned short* y2 = (unsigned short*)(ws);
    float*          yc = (float*)(ws);
    unsigned short* y1 = (unsigned short*)(ws + 169869312L);
    float*     partial = (float*)(ws + 169869312L + 42467328L);
    float*         gx2 = partial + 864L * C4;
    float*         snx = gx2 + C4;
    float*        beff = snx + C4;

    bias_eff_k<<<1, 192, 0, stream>>>(gb, w2, b2, beff);

    for (int b = 0; b < Bn; ++b) {
        const float* xb = x + (size_t)b * CDHW;
        float* outb = out + (size_t)b * CDHW;
        dim3 gc(54, Cn);                  // 6x3x3 spatial tiles, per channel
        conv_dw<<<gc, 128, 0, stream>>>(xb, conv_w, conv_b, yc);
        ln_kernel<<<Dn * Hn, 256, 0, stream>>>(yc, ln_g, ln_b, y1);
        dim3 gu(DHW / 64, C4 / 64);
        gemm_up<<<gu, 256, 0, stream>>>(y1, w1, b1, y2);
        grn_stats<<<DHW / 128, 256, 0, stream>>>(y2, partial);
        grn_reduce<<<C4, 256, 0, stream>>>(partial, gx2);
        grn_snx<<<1, 256, 0, stream>>>(gx2, gg, snx);
        dim3 gd(DHW / 64, Cn / 64);
        gemm_down<<<gd, 256, 0, stream>>>(y2, w2, snx, beff, xb, outb);
    }
}

// Round 4
// 1338.498 us; speedup vs baseline: 5.0369x; 2.0408x over previous
//
#include <hip/hip_runtime.h>
#include <math.h>

#define Bn 2
#define Cn 192
#define Dn 48
#define Hn 48
#define Wn 48
#define C4 768
#define DHW (Dn*Hn*Wn)          // 110592 per batch
#define CDHW ((long)Cn*DHW)     // 21233664 per batch

typedef __attribute__((ext_vector_type(8))) short bf16x8;
typedef __attribute__((ext_vector_type(4))) float f32x4;

__device__ inline float bf2f(unsigned short u) {
    union { float f; unsigned int i; } v; v.i = ((unsigned int)u) << 16; return v.f;
}
__device__ inline unsigned short f2bf(float f) {
    union { float f; unsigned int i; } v; v.f = f;
    unsigned int r = v.i + 0x7FFFu + ((v.i >> 16) & 1u);   // RNE
    return (unsigned short)(r >> 16);
}

// ---------------- depthwise conv 7x7x7, LDS-tiled, per-batch NCDHW -> NCDHW ----
#define TD 8
#define TH 16
#define TW 16
#define HD (TD+6)     // 14
#define HH (TH+6)     // 22
#define HW (TW+6)     // 22
#define HWP 23        // padded w stride
#define HALO (HD*HH*HW)

__global__ __launch_bounds__(128)
void conv_dw(const float* __restrict__ x, const float* __restrict__ cw,
             const float* __restrict__ cb, float* __restrict__ yc)
{
    __shared__ float xt[HD][HH][HWP];
    __shared__ float wl[343];
    int c = blockIdx.y;
    int s = blockIdx.x;
    int wt = s % 3, ht = (s / 3) % 3, dt = s / 9;
    int d0 = dt * TD, h0 = ht * TH, w0 = wt * TW;
    int tid = threadIdx.x;

    for (int i = tid; i < 343; i += 128) wl[i] = cw[i * Cn + c];

    const float* xb = x + (long)c * DHW;
    for (int i = tid; i < HALO; i += 128) {
        int dd = i / (HH * HW);
        int r  = i % (HH * HW);
        int hh = r / HW, ww = r % HW;
        int gd = d0 - 3 + dd, gh = h0 - 3 + hh, gw = w0 - 3 + ww;
        bool ok = (unsigned)gd < 48u && (unsigned)gh < 48u && (unsigned)gw < 48u;
        xt[dd][hh][ww] = ok ? xb[(gd * 48 + gh) * 48 + gw] : 0.0f;
    }
    __syncthreads();

    int wg = tid & 1;
    int hh = (tid >> 1) & 15;
    int dp = tid >> 5;
    float bias = cb[c];
    float acc[2][8];
#pragma unroll
    for (int t = 0; t < 2; ++t)
#pragma unroll
        for (int i = 0; i < 8; ++i) acc[t][i] = bias;

    for (int kh = 0; kh < 7; ++kh) {
        int hin = hh + kh;
#pragma unroll
        for (int rr = 0; rr < 8; ++rr) {
            int din = dp * 2 + rr;
            float xr[14];
#pragma unroll
            for (int j = 0; j < 14; ++j) xr[j] = xt[din][hin][wg * 8 + j];
#pragma unroll
            for (int t = 0; t < 2; ++t) {
                int kd = rr - t;
                if (kd < 0 || kd > 6) continue;
                const float* wr = wl + (kd * 7 + kh) * 7;
#pragma unroll
                for (int kw = 0; kw < 7; ++kw) {
                    float wv = wr[kw];
#pragma unroll
                    for (int i = 0; i < 8; ++i)
                        acc[t][i] = fmaf(xr[kw + i], wv, acc[t][i]);
                }
            }
        }
    }

    float* yb = yc + (long)c * DHW;
#pragma unroll
    for (int t = 0; t < 2; ++t) {
        int dout = d0 + dp * 2 + t;
        float* op = yb + (dout * 48 + h0 + hh) * 48 + w0 + wg * 8;
        *(float4*)op       = *(float4*)&acc[t][0];
        *(float4*)(op + 4) = *(float4*)&acc[t][4];
    }
}

// ---------------- LayerNorm over C, per-batch NCDHW -> NDHWC (bf16 out) ----------------
__global__ __launch_bounds__(256)
void ln_kernel(const float* __restrict__ yc, const float* __restrict__ g,
               const float* __restrict__ lb, unsigned short* __restrict__ y1)
{
    __shared__ float tile[Cn * Wn];
    __shared__ float mu_s[Wn], rs_s[Wn];
    int dh = blockIdx.x;
    long rowbase = (long)dh * Wn;
    for (int l = threadIdx.x; l < Cn * Wn; l += 256) {
        int c = l / Wn, w = l % Wn;
        tile[l] = yc[rowbase + (long)c * DHW + w];
    }
    __syncthreads();
    if (threadIdx.x < Wn) {
        int w = threadIdx.x;
        float s = 0.f;
        for (int c = 0; c < Cn; ++c) s += tile[c * Wn + w];
        float mu = s * (1.0f / Cn);
        float v = 0.f;
        for (int c = 0; c < Cn; ++c) { float dd = tile[c * Wn + w] - mu; v = fmaf(dd, dd, v); }
        mu_s[w] = mu;
        rs_s[w] = rsqrtf(v * (1.0f / Cn) + 1e-6f);
    }
    __syncthreads();
    long obase = (long)dh * Wn * Cn;
    for (int l = threadIdx.x; l < Cn * Wn; l += 256) {
        int w = l / Cn, c = l % Cn;
        float val = (tile[c * Wn + w] - mu_s[w]) * rs_s[w] * g[c] + lb[c];
        y1[obase + l] = f2bf(val);
    }
}

// ---------------- weight transpose+bf16: Wt[n][k] = bf16(W[k][n]) ----------------
__global__ __launch_bounds__(256)
void wtrans(const float* __restrict__ W, unsigned short* __restrict__ Wt, int K, int N)
{
    int idx = blockIdx.x * 256 + threadIdx.x;
    if (idx >= K * N) return;
    int n = idx / K, k = idx % K;
    Wt[idx] = f2bf(W[(long)k * N + n]);
}

// ---------------- W2 scale+transpose: W2s[n][k] = bf16(W2[k][n]*snx[k]) ----------------
__global__ __launch_bounds__(256)
void wscale(const float* __restrict__ W2, const float* __restrict__ snx,
            unsigned short* __restrict__ W2s)
{
    int idx = blockIdx.x * 256 + threadIdx.x;
    if (idx >= C4 * Cn) return;
    int n = idx / C4, k = idx % C4;
    W2s[idx] = f2bf(W2[(long)k * Cn + n] * snx[k]);
}

// ================= MFMA GEMM: C[M,N] = A[M,K](bf16) @ Bt[N,K](bf16)^T =========
// block 256 thr = 4 waves (2M x 2N), BM=128 BN=64 BK=64, XOR-swizzled LDS.
#define BM 128
#define BN 64
#define BK 64

#define GEMM_STAGE(Aptr, Astride, Btptr, Bstride)                               \
    {                                                                           \
        _Pragma("unroll")                                                       \
        for (int i = 0; i < 4; ++i) {                                           \
            int chunk = i * 256 + tid;                                          \
            int r = chunk >> 3, cc = chunk & 7;                                 \
            bf16x8 v = *(const bf16x8*)((Aptr) + (size_t)(m0 + r) * (Astride) + k0 + cc * 8); \
            *(bf16x8*)&Asm[r * BK + ((cc ^ (r & 7)) * 8)] = v;                  \
        }                                                                       \
        _Pragma("unroll")                                                       \
        for (int i = 0; i < 2; ++i) {                                           \
            int chunk = i * 256 + tid;                                          \
            int r = chunk >> 3, cc = chunk & 7;                                 \
            bf16x8 v = *(const bf16x8*)((Btptr) + (size_t)(n0 + r) * (Bstride) + k0 + cc * 8); \
            *(bf16x8*)&Bsm[r * BK + ((cc ^ (r & 7)) * 8)] = v;                  \
        }                                                                       \
    }

#define GEMM_COMPUTE                                                            \
    _Pragma("unroll")                                                           \
    for (int kk = 0; kk < 2; ++kk) {                                            \
        bf16x8 af[4], bfr[2];                                                   \
        _Pragma("unroll")                                                       \
        for (int mi = 0; mi < 4; ++mi) {                                        \
            int r = wm * 64 + mi * 16 + lr;                                     \
            int cc = (kk * 4 + lq) ^ (r & 7);                                   \
            af[mi] = *(const bf16x8*)&Asm[r * BK + cc * 8];                     \
        }                                                                       \
        _Pragma("unroll")                                                       \
        for (int ni = 0; ni < 2; ++ni) {                                        \
            int r = wn * 32 + ni * 16 + lr;                                     \
            int cc = (kk * 4 + lq) ^ (r & 7);                                   \
            bfr[ni] = *(const bf16x8*)&Bsm[r * BK + cc * 8];                    \
        }                                                                       \
        _Pragma("unroll")                                                       \
        for (int mi = 0; mi < 4; ++mi)                                          \
            _Pragma("unroll")                                                   \
            for (int ni = 0; ni < 2; ++ni)                                      \
                acc[mi][ni] = __builtin_amdgcn_mfma_f32_16x16x32_bf16(          \
                    af[mi], bfr[ni], acc[mi][ni], 0, 0, 0);                     \
    }

// ---- GEMM up: y1[M,192] @ w1t[768,192]^T + b1, exact GELU -> y2 bf16 [M,768] ----
__global__ __launch_bounds__(256)
void gemm_up(const unsigned short* __restrict__ A, const unsigned short* __restrict__ Bt,
             const float* __restrict__ bias, unsigned short* __restrict__ Y2)
{
    __shared__ short Asm[BM * BK];
    __shared__ short Bsm[BN * BK];
    int tid = threadIdx.x;
    int lane = tid & 63, wv = tid >> 6;
    int wm = wv >> 1, wn = wv & 1;
    int lr = lane & 15, lq = lane >> 4;
    long m0 = (long)blockIdx.y * BM;
    int n0 = blockIdx.x * BN;

    f32x4 acc[4][2];
#pragma unroll
    for (int mi = 0; mi < 4; ++mi)
#pragma unroll
        for (int ni = 0; ni < 2; ++ni) acc[mi][ni] = (f32x4){0.f, 0.f, 0.f, 0.f};

    for (int k0 = 0; k0 < Cn; k0 += BK) {
        GEMM_STAGE(A, Cn, Bt, Cn);
        __syncthreads();
        GEMM_COMPUTE;
        __syncthreads();
    }

#pragma unroll
    for (int mi = 0; mi < 4; ++mi) {
#pragma unroll
        for (int ni = 0; ni < 2; ++ni) {
            int colg = n0 + wn * 32 + ni * 16 + lr;
            float bb = bias[colg];
            long mbase = m0 + wm * 64 + mi * 16 + lq * 4;
#pragma unroll
            for (int i = 0; i < 4; ++i) {
                float v = acc[mi][ni][i] + bb;
                v = 0.5f * v * (1.0f + erff(v * 0.70710678118654752f));
                Y2[(mbase + i) * C4 + colg] = f2bf(v);
            }
        }
    }
}

// ---- GEMM down: y2[M,768] @ w2s[192,768]^T + beff + x, NDHWC -> NCDHW f32 ----
__global__ __launch_bounds__(256)
void gemm_down(const unsigned short* __restrict__ A, const unsigned short* __restrict__ Bt,
               const float* __restrict__ beff, const float* __restrict__ x,
               float* __restrict__ out)
{
    __shared__ short Asm[BM * BK];
    __shared__ short Bsm[BN * BK];
    int tid = threadIdx.x;
    int lane = tid & 63, wv = tid >> 6;
    int wm = wv >> 1, wn = wv & 1;
    int lr = lane & 15, lq = lane >> 4;
    long m0 = (long)blockIdx.y * BM;
    int n0 = blockIdx.x * BN;

    f32x4 acc[4][2];
#pragma unroll
    for (int mi = 0; mi < 4; ++mi)
#pragma unroll
        for (int ni = 0; ni < 2; ++ni) acc[mi][ni] = (f32x4){0.f, 0.f, 0.f, 0.f};

    for (int k0 = 0; k0 < C4; k0 += BK) {
        GEMM_STAGE(A, C4, Bt, C4);
        __syncthreads();
        GEMM_COMPUTE;
        __syncthreads();
    }

#pragma unroll
    for (int mi = 0; mi < 4; ++mi) {
#pragma unroll
        for (int ni = 0; ni < 2; ++ni) {
            int colg = n0 + wn * 32 + ni * 16 + lr;   // output channel c
            float be = beff[colg];
            long mbase = m0 + wm * 64 + mi * 16 + lq * 4;
            const float* xp = x + (long)colg * DHW + mbase;
            float* op = out + (long)colg * DHW + mbase;
            float4 xv = *(const float4*)xp;
            float4 o;
            o.x = acc[mi][ni][0] + be + xv.x;
            o.y = acc[mi][ni][1] + be + xv.y;
            o.z = acc[mi][ni][2] + be + xv.z;
            o.w = acc[mi][ni][3] + be + xv.w;
            *(float4*)op = o;
        }
    }
}

// ---------------- GRN stats: per-block partial sums of squares (bf16 in) ----------------
__global__ __launch_bounds__(256)
void grn_stats(const unsigned short* __restrict__ Y2, float* __restrict__ partial)
{
    long m0 = (long)blockIdx.x * 128;
    float s0 = 0.f, s1 = 0.f, s2 = 0.f;
    for (int r = 0; r < 128; ++r) {
        const unsigned short* row = Y2 + (m0 + r) * C4;
        float v0 = bf2f(row[threadIdx.x]);       s0 = fmaf(v0, v0, s0);
        float v1 = bf2f(row[threadIdx.x + 256]); s1 = fmaf(v1, v1, s1);
        float v2 = bf2f(row[threadIdx.x + 512]); s2 = fmaf(v2, v2, s2);
    }
    float* p = partial + (long)blockIdx.x * C4;
    p[threadIdx.x] = s0; p[threadIdx.x + 256] = s1; p[threadIdx.x + 512] = s2;
}

// ---------------- GRN reduce: 864 partials -> gx2[n] ----------------
__global__ __launch_bounds__(256)
void grn_reduce(const float* __restrict__ partial, float* __restrict__ gx2)
{
    int n = blockIdx.x;
    const float* p = partial + n;
    float s = 0.f;
    for (int r = threadIdx.x; r < 864; r += 256) s += p[(long)r * C4];
    __shared__ float red[256];
    red[threadIdx.x] = s; __syncthreads();
    for (int st = 128; st > 0; st >>= 1) {
        if (threadIdx.x < st) red[threadIdx.x] += red[threadIdx.x + st];
        __syncthreads();
    }
    if (threadIdx.x == 0) gx2[n] = red[0];
}

// ---------------- GRN scale: snx[n] = 1 + gamma[n]*nx ----------------
__global__ __launch_bounds__(256)
void grn_snx(const float* __restrict__ gx2, const float* __restrict__ gamma,
             float* __restrict__ snx)
{
    __shared__ float red[256];
    float gx[3]; float s = 0.f;
#pragma unroll
    for (int i = 0; i < 3; ++i) {
        int n = threadIdx.x + i * 256;
        gx[i] = sqrtf(gx2[n]);
        s += gx[i];
    }
    red[threadIdx.x] = s; __syncthreads();
    for (int st = 128; st > 0; st >>= 1) {
        if (threadIdx.x < st) red[threadIdx.x] += red[threadIdx.x + st];
        __syncthreads();
    }
    float inv = 1.0f / (red[0] * (1.0f / C4) + 1e-6f);
#pragma unroll
    for (int i = 0; i < 3; ++i) {
        int n = threadIdx.x + i * 256;
        snx[n] = 1.0f + gamma[n] * gx[i] * inv;
    }
}

// ---------------- effective down-bias: beff = b2 + beta @ W2 ----------------
__global__ __launch_bounds__(192)
void bias_eff_k(const float* __restrict__ beta, const float* __restrict__ W2,
                const float* __restrict__ b2, float* __restrict__ beff)
{
    int j = threadIdx.x;
    float s = b2[j];
    for (int k = 0; k < C4; ++k) s = fmaf(beta[k], W2[k * Cn + j], s);
    beff[j] = s;
}

extern "C" void kernel_launch(void* const* d_in, const int* in_sizes, int n_in,
                              void* d_out, int out_size, void* d_ws, size_t ws_size,
                              hipStream_t stream) {
    const float* x      = (const float*)d_in[0];
    const float* conv_w = (const float*)d_in[1];
    const float* conv_b = (const float*)d_in[2];
    const float* ln_g   = (const float*)d_in[3];
    const float* ln_b   = (const float*)d_in[4];
    const float* w1     = (const float*)d_in[5];
    const float* b1     = (const float*)d_in[6];
    const float* gg     = (const float*)d_in[7];
    const float* gb     = (const float*)d_in[8];
    const float* w2     = (const float*)d_in[9];
    const float* b2     = (const float*)d_in[10];
    float* out = (float*)d_out;
    char* ws = (char*)d_ws;

    // ws layout (~216 MB):
    unsigned short* y2  = (unsigned short*)(ws);                  // [M][768] bf16, overlaps yc
    float*          yc  = (float*)(ws);                           // [192][DHW] f32
    unsigned short* y1  = (unsigned short*)(ws + 169869312L);     // [M][192] bf16
    float*     partial  = (float*)(ws + 212336640L);              // [864][768] f32
    unsigned short* w1t = (unsigned short*)(ws + 214990848L);     // [768][192] bf16
    unsigned short* w2s = (unsigned short*)(ws + 215285760L);     // [192][768] bf16
    float*         gx2  = (float*)(ws + 215580672L);
    float*         snx  = (float*)(ws + 215583744L);
    float*        beff  = (float*)(ws + 215586816L);

    bias_eff_k<<<1, 192, 0, stream>>>(gb, w2, b2, beff);
    wtrans<<<(Cn * C4 + 255) / 256, 256, 0, stream>>>(w1, w1t, Cn, C4);

    for (int b = 0; b < Bn; ++b) {
        const float* xb = x + (size_t)b * CDHW;
        float* outb = out + (size_t)b * CDHW;
        dim3 gc(54, Cn);
        conv_dw<<<gc, 128, 0, stream>>>(xb, conv_w, conv_b, yc);
        ln_kernel<<<Dn * Hn, 256, 0, stream>>>(yc, ln_g, ln_b, y1);
        dim3 gu(C4 / BN, DHW / BM);       // (12, 864) — nblk fast for L2 A-reuse
        gemm_up<<<gu, 256, 0, stream>>>(y1, w1t, b1, y2);
        grn_stats<<<DHW / 128, 256, 0, stream>>>(y2, partial);
        grn_reduce<<<C4, 256, 0, stream>>>(partial, gx2);
        grn_snx<<<1, 256, 0, stream>>>(gx2, gg, snx);
        wscale<<<(Cn * C4 + 255) / 256, 256, 0, stream>>>(w2, snx, w2s);
        dim3 gd(Cn / BN, DHW / BM);       // (3, 864)
        gemm_down<<<gd, 256, 0, stream>>>(y2, w2s, beff, xb, outb);
    }
}

// Round 5
// 1131.402 us; speedup vs baseline: 5.9588x; 1.1830x over previous
//
#include <hip/hip_runtime.h>
#include <math.h>

#define Bn 2
#define Cn 192
#define Dn 48
#define Hn 48
#define Wn 48
#define C4 768
#define DHW (Dn*Hn*Wn)          // 110592 per batch
#define CDHW ((long)Cn*DHW)     // 21233664 per batch

typedef __attribute__((ext_vector_type(8))) short bf16x8;
typedef __attribute__((ext_vector_type(4))) float f32x4;

__device__ inline float bf2f(unsigned short u) {
    union { float f; unsigned int i; } v; v.i = ((unsigned int)u) << 16; return v.f;
}
__device__ inline unsigned short f2bf(float f) {
    union { float f; unsigned int i; } v; v.f = f;
    unsigned int r = v.i + 0x7FFFu + ((v.i >> 16) & 1u);   // RNE
    return (unsigned short)(r >> 16);
}

// ---------------- depthwise conv 7x7x7, bf16 LDS halo, per-batch NCDHW -> NCDHW ----
// block: 128 threads, one channel, 8(d)x16(h)x16(w) output tile.
// thread: 2(d)x8(w) register tile at one h. Halo 14x22x22 staged as bf16,
// row stride 24 shorts (48B -> <=2-way bank aliasing, free).
#define TD 8
#define TH 16
#define TW 16
#define HD (TD+6)     // 14
#define HH (TH+6)     // 22
#define HWS 24        // padded w stride in shorts

__global__ __launch_bounds__(128)
void conv_dw(const float* __restrict__ x, const float* __restrict__ cw,
             const float* __restrict__ cb, float* __restrict__ yc)
{
    __shared__ unsigned short xt[HD][HH][HWS];   // 14,784 B
    __shared__ float wl[343];
    int c = blockIdx.y;
    int s = blockIdx.x;                   // 54 spatial tiles: 6(d) x 3(h) x 3(w)
    int wt = s % 3, ht = (s / 3) % 3, dt = s / 9;
    int d0 = dt * TD, h0 = ht * TH, w0 = wt * TW;
    int tid = threadIdx.x;

    for (int i = tid; i < 343; i += 128) wl[i] = cw[i * Cn + c];

    const float* xb = x + (long)c * DHW;
    // stage halo: 14*22 rows x 12 bf16-pairs per row (24 shorts incl. 2 pad)
    for (int u = tid; u < HD * HH * 12; u += 128) {
        int pair = u % 12;
        int row = u / 12;
        int hh2 = row % HH, dd = row / HH;
        int gd = d0 - 3 + dd, gh = h0 - 3 + hh2;
        int gw0 = w0 - 3 + pair * 2;
        bool okp = (unsigned)gd < 48u && (unsigned)gh < 48u;
        const float* xr0 = xb + (gd * 48 + gh) * 48;
        float v0 = (okp && (unsigned)gw0 < 48u) ? xr0[gw0] : 0.0f;
        float v1 = (okp && (unsigned)(gw0 + 1) < 48u) ? xr0[gw0 + 1] : 0.0f;
        unsigned int packed = (unsigned)f2bf(v0) | ((unsigned)f2bf(v1) << 16);
        *(unsigned int*)&xt[dd][hh2][pair * 2] = packed;
    }
    __syncthreads();

    int wg = tid & 1;                     // w half (8 outputs)
    int hh = (tid >> 1) & 15;             // output h within tile
    int dp = tid >> 5;                    // d pair index [0,4)
    float bias = cb[c];
    float acc[2][8];
#pragma unroll
    for (int t = 0; t < 2; ++t)
#pragma unroll
        for (int i = 0; i < 8; ++i) acc[t][i] = bias;

    for (int kh = 0; kh < 7; ++kh) {
        int hin = hh + kh;
#pragma unroll
        for (int rr = 0; rr < 8; ++rr) {
            int din = dp * 2 + rr;
            // 16-bf16 window via 2x ds_read_b128 (14 used)
            unsigned short xs[16];
            *(uint4*)&xs[0] = *(const uint4*)&xt[din][hin][wg * 8];
            *(uint4*)&xs[8] = *(const uint4*)&xt[din][hin][wg * 8 + 8];
            float xr[14];
#pragma unroll
            for (int j = 0; j < 14; ++j) xr[j] = bf2f(xs[j]);
#pragma unroll
            for (int t = 0; t < 2; ++t) {
                int kd = rr - t;
                if (kd < 0 || kd > 6) continue;
                const float* wr = wl + (kd * 7 + kh) * 7;
#pragma unroll
                for (int kw = 0; kw < 7; ++kw) {
                    float wv = wr[kw];
#pragma unroll
                    for (int i = 0; i < 8; ++i)
                        acc[t][i] = fmaf(xr[kw + i], wv, acc[t][i]);
                }
            }
        }
    }

    float* yb = yc + (long)c * DHW;
#pragma unroll
    for (int t = 0; t < 2; ++t) {
        int dout = d0 + dp * 2 + t;
        float* op = yb + (dout * 48 + h0 + hh) * 48 + w0 + wg * 8;
        *(float4*)op       = *(float4*)&acc[t][0];
        *(float4*)(op + 4) = *(float4*)&acc[t][4];
    }
}

// ---------------- LayerNorm over C, per-batch NCDHW -> NDHWC (bf16 out) ----------------
__global__ __launch_bounds__(256)
void ln_kernel(const float* __restrict__ yc, const float* __restrict__ g,
               const float* __restrict__ lb, unsigned short* __restrict__ y1)
{
    __shared__ float tile[Cn * Wn];
    __shared__ float mu_s[Wn], rs_s[Wn];
    int dh = blockIdx.x;
    long rowbase = (long)dh * Wn;
    for (int l = threadIdx.x; l < Cn * Wn; l += 256) {
        int c = l / Wn, w = l % Wn;
        tile[l] = yc[rowbase + (long)c * DHW + w];
    }
    __syncthreads();
    if (threadIdx.x < Wn) {
        int w = threadIdx.x;
        float s = 0.f;
        for (int c = 0; c < Cn; ++c) s += tile[c * Wn + w];
        float mu = s * (1.0f / Cn);
        float v = 0.f;
        for (int c = 0; c < Cn; ++c) { float dd = tile[c * Wn + w] - mu; v = fmaf(dd, dd, v); }
        mu_s[w] = mu;
        rs_s[w] = rsqrtf(v * (1.0f / Cn) + 1e-6f);
    }
    __syncthreads();
    long obase = (long)dh * Wn * Cn;
    for (int l = threadIdx.x; l < Cn * Wn; l += 256) {
        int w = l / Cn, c = l % Cn;
        float val = (tile[c * Wn + w] - mu_s[w]) * rs_s[w] * g[c] + lb[c];
        y1[obase + l] = f2bf(val);
    }
}

// ---------------- weight transpose+bf16: Wt[n][k] = bf16(W[k][n]) ----------------
__global__ __launch_bounds__(256)
void wtrans(const float* __restrict__ W, unsigned short* __restrict__ Wt, int K, int N)
{
    int idx = blockIdx.x * 256 + threadIdx.x;
    if (idx >= K * N) return;
    int n = idx / K, k = idx % K;
    Wt[idx] = f2bf(W[(long)k * N + n]);
}

// ---------------- W2 scale+transpose: W2s[n][k] = bf16(W2[k][n]*snx[k]) ----------------
__global__ __launch_bounds__(256)
void wscale(const float* __restrict__ W2, const float* __restrict__ snx,
            unsigned short* __restrict__ W2s)
{
    int idx = blockIdx.x * 256 + threadIdx.x;
    if (idx >= C4 * Cn) return;
    int n = idx / C4, k = idx % C4;
    W2s[idx] = f2bf(W2[(long)k * Cn + n] * snx[k]);
}

// ================= MFMA GEMM: C[M,N] = A[M,K](bf16) @ Bt[N,K](bf16)^T =========
#define BM 128
#define BN 64
#define BK 64

#define GEMM_STAGE(Aptr, Astride, Btptr, Bstride)                               \
    {                                                                           \
        _Pragma("unroll")                                                       \
        for (int i = 0; i < 4; ++i) {                                           \
            int chunk = i * 256 + tid;                                          \
            int r = chunk >> 3, cc = chunk & 7;                                 \
            bf16x8 v = *(const bf16x8*)((Aptr) + (size_t)(m0 + r) * (Astride) + k0 + cc * 8); \
            *(bf16x8*)&Asm[r * BK + ((cc ^ (r & 7)) * 8)] = v;                  \
        }                                                                       \
        _Pragma("unroll")                                                       \
        for (int i = 0; i < 2; ++i) {                                           \
            int chunk = i * 256 + tid;                                          \
            int r = chunk >> 3, cc = chunk & 7;                                 \
            bf16x8 v = *(const bf16x8*)((Btptr) + (size_t)(n0 + r) * (Bstride) + k0 + cc * 8); \
            *(bf16x8*)&Bsm[r * BK + ((cc ^ (r & 7)) * 8)] = v;                  \
        }                                                                       \
    }

#define GEMM_COMPUTE                                                            \
    _Pragma("unroll")                                                           \
    for (int kk = 0; kk < 2; ++kk) {                                            \
        bf16x8 af[4], bfr[2];                                                   \
        _Pragma("unroll")                                                       \
        for (int mi = 0; mi < 4; ++mi) {                                        \
            int r = wm * 64 + mi * 16 + lr;                                     \
            int cc = (kk * 4 + lq) ^ (r & 7);                                   \
            af[mi] = *(const bf16x8*)&Asm[r * BK + cc * 8];                     \
        }                                                                       \
        _Pragma("unroll")                                                       \
        for (int ni = 0; ni < 2; ++ni) {                                        \
            int r = wn * 32 + ni * 16 + lr;                                     \
            int cc = (kk * 4 + lq) ^ (r & 7);                                   \
            bfr[ni] = *(const bf16x8*)&Bsm[r * BK + cc * 8];                    \
        }                                                                       \
        _Pragma("unroll")                                                       \
        for (int mi = 0; mi < 4; ++mi)                                          \
            _Pragma("unroll")                                                   \
            for (int ni = 0; ni < 2; ++ni)                                      \
                acc[mi][ni] = __builtin_amdgcn_mfma_f32_16x16x32_bf16(          \
                    af[mi], bfr[ni], acc[mi][ni], 0, 0, 0);                     \
    }

// ---- GEMM up: y1[M,192] @ w1t[768,192]^T + b1, exact GELU -> y2 bf16 [M,768] ----
__global__ __launch_bounds__(256)
void gemm_up(const unsigned short* __restrict__ A, const unsigned short* __restrict__ Bt,
             const float* __restrict__ bias, unsigned short* __restrict__ Y2)
{
    __shared__ short Asm[BM * BK];
    __shared__ short Bsm[BN * BK];
    int tid = threadIdx.x;
    int lane = tid & 63, wv = tid >> 6;
    int wm = wv >> 1, wn = wv & 1;
    int lr = lane & 15, lq = lane >> 4;
    long m0 = (long)blockIdx.y * BM;
    int n0 = blockIdx.x * BN;

    f32x4 acc[4][2];
#pragma unroll
    for (int mi = 0; mi < 4; ++mi)
#pragma unroll
        for (int ni = 0; ni < 2; ++ni) acc[mi][ni] = (f32x4){0.f, 0.f, 0.f, 0.f};

    for (int k0 = 0; k0 < Cn; k0 += BK) {
        GEMM_STAGE(A, Cn, Bt, Cn);
        __syncthreads();
        GEMM_COMPUTE;
        __syncthreads();
    }

#pragma unroll
    for (int mi = 0; mi < 4; ++mi) {
#pragma unroll
        for (int ni = 0; ni < 2; ++ni) {
            int colg = n0 + wn * 32 + ni * 16 + lr;
            float bb = bias[colg];
            long mbase = m0 + wm * 64 + mi * 16 + lq * 4;
#pragma unroll
            for (int i = 0; i < 4; ++i) {
                float v = acc[mi][ni][i] + bb;
                v = 0.5f * v * (1.0f + erff(v * 0.70710678118654752f));
                Y2[(mbase + i) * C4 + colg] = f2bf(v);
            }
        }
    }
}

// ---- GEMM down: y2[M,768] @ w2s[192,768]^T + beff + x, NDHWC -> NCDHW f32 ----
__global__ __launch_bounds__(256)
void gemm_down(const unsigned short* __restrict__ A, const unsigned short* __restrict__ Bt,
               const float* __restrict__ beff, const float* __restrict__ x,
               float* __restrict__ out)
{
    __shared__ short Asm[BM * BK];
    __shared__ short Bsm[BN * BK];
    int tid = threadIdx.x;
    int lane = tid & 63, wv = tid >> 6;
    int wm = wv >> 1, wn = wv & 1;
    int lr = lane & 15, lq = lane >> 4;
    long m0 = (long)blockIdx.y * BM;
    int n0 = blockIdx.x * BN;

    f32x4 acc[4][2];
#pragma unroll
    for (int mi = 0; mi < 4; ++mi)
#pragma unroll
        for (int ni = 0; ni < 2; ++ni) acc[mi][ni] = (f32x4){0.f, 0.f, 0.f, 0.f};

    for (int k0 = 0; k0 < C4; k0 += BK) {
        GEMM_STAGE(A, C4, Bt, C4);
        __syncthreads();
        GEMM_COMPUTE;
        __syncthreads();
    }

#pragma unroll
    for (int mi = 0; mi < 4; ++mi) {
#pragma unroll
        for (int ni = 0; ni < 2; ++ni) {
            int colg = n0 + wn * 32 + ni * 16 + lr;   // output channel c
            float be = beff[colg];
            long mbase = m0 + wm * 64 + mi * 16 + lq * 4;
            const float* xp = x + (long)colg * DHW + mbase;
            float* op = out + (long)colg * DHW + mbase;
            float4 xv = *(const float4*)xp;
            float4 o;
            o.x = acc[mi][ni][0] + be + xv.x;
            o.y = acc[mi][ni][1] + be + xv.y;
            o.z = acc[mi][ni][2] + be + xv.z;
            o.w = acc[mi][ni][3] + be + xv.w;
            *(float4*)op = o;
        }
    }
}

// ---------------- GRN stats ----------------
__global__ __launch_bounds__(256)
void grn_stats(const unsigned short* __restrict__ Y2, float* __restrict__ partial)
{
    long m0 = (long)blockIdx.x * 128;
    float s0 = 0.f, s1 = 0.f, s2 = 0.f;
    for (int r = 0; r < 128; ++r) {
        const unsigned short* row = Y2 + (m0 + r) * C4;
        float v0 = bf2f(row[threadIdx.x]);       s0 = fmaf(v0, v0, s0);
        float v1 = bf2f(row[threadIdx.x + 256]); s1 = fmaf(v1, v1, s1);
        float v2 = bf2f(row[threadIdx.x + 512]); s2 = fmaf(v2, v2, s2);
    }
    float* p = partial + (long)blockIdx.x * C4;
    p[threadIdx.x] = s0; p[threadIdx.x + 256] = s1; p[threadIdx.x + 512] = s2;
}

// ---------------- GRN reduce ----------------
__global__ __launch_bounds__(256)
void grn_reduce(const float* __restrict__ partial, float* __restrict__ gx2)
{
    int n = blockIdx.x;
    const float* p = partial + n;
    float s = 0.f;
    for (int r = threadIdx.x; r < 864; r += 256) s += p[(long)r * C4];
    __shared__ float red[256];
    red[threadIdx.x] = s; __syncthreads();
    for (int st = 128; st > 0; st >>= 1) {
        if (threadIdx.x < st) red[threadIdx.x] += red[threadIdx.x + st];
        __syncthreads();
    }
    if (threadIdx.x == 0) gx2[n] = red[0];
}

// ---------------- GRN scale ----------------
__global__ __launch_bounds__(256)
void grn_snx(const float* __restrict__ gx2, const float* __restrict__ gamma,
             float* __restrict__ snx)
{
    __shared__ float red[256];
    float gx[3]; float s = 0.f;
#pragma unroll
    for (int i = 0; i < 3; ++i) {
        int n = threadIdx.x + i * 256;
        gx[i] = sqrtf(gx2[n]);
        s += gx[i];
    }
    red[threadIdx.x] = s; __syncthreads();
    for (int st = 128; st > 0; st >>= 1) {
        if (threadIdx.x < st) red[threadIdx.x] += red[threadIdx.x + st];
        __syncthreads();
    }
    float inv = 1.0f / (red[0] * (1.0f / C4) + 1e-6f);
#pragma unroll
    for (int i = 0; i < 3; ++i) {
        int n = threadIdx.x + i * 256;
        snx[n] = 1.0f + gamma[n] * gx[i] * inv;
    }
}

// ---------------- effective down-bias ----------------
__global__ __launch_bounds__(192)
void bias_eff_k(const float* __restrict__ beta, const float* __restrict__ W2,
                const float* __restrict__ b2, float* __restrict__ beff)
{
    int j = threadIdx.x;
    float s = b2[j];
    for (int k = 0; k < C4; ++k) s = fmaf(beta[k], W2[k * Cn + j], s);
    beff[j] = s;
}

extern "C" void kernel_launch(void* const* d_in, const int* in_sizes, int n_in,
                              void* d_out, int out_size, void* d_ws, size_t ws_size,
                              hipStream_t stream) {
    const float* x      = (const float*)d_in[0];
    const float* conv_w = (const float*)d_in[1];
    const float* conv_b = (const float*)d_in[2];
    const float* ln_g   = (const float*)d_in[3];
    const float* ln_b   = (const float*)d_in[4];
    const float* w1     = (const float*)d_in[5];
    const float* b1     = (const float*)d_in[6];
    const float* gg     = (const float*)d_in[7];
    const float* gb     = (const float*)d_in[8];
    const float* w2     = (const float*)d_in[9];
    const float* b2     = (const float*)d_in[10];
    float* out = (float*)d_out;
    char* ws = (char*)d_ws;

    unsigned short* y2  = (unsigned short*)(ws);                  // [M][768] bf16, overlaps yc
    float*          yc  = (float*)(ws);                           // [192][DHW] f32
    unsigned short* y1  = (unsigned short*)(ws + 169869312L);     // [M][192] bf16
    float*     partial  = (float*)(ws + 212336640L);              // [864][768] f32
    unsigned short* w1t = (unsigned short*)(ws + 214990848L);     // [768][192] bf16
    unsigned short* w2s = (unsigned short*)(ws + 215285760L);     // [192][768] bf16
    float*         gx2  = (float*)(ws + 215580672L);
    float*         snx  = (float*)(ws + 215583744L);
    float*        beff  = (float*)(ws + 215586816L);

    bias_eff_k<<<1, 192, 0, stream>>>(gb, w2, b2, beff);
    wtrans<<<(Cn * C4 + 255) / 256, 256, 0, stream>>>(w1, w1t, Cn, C4);

    for (int b = 0; b < Bn; ++b) {
        const float* xb = x + (size_t)b * CDHW;
        float* outb = out + (size_t)b * CDHW;
        dim3 gc(54, Cn);
        conv_dw<<<gc, 128, 0, stream>>>(xb, conv_w, conv_b, yc);
        ln_kernel<<<Dn * Hn, 256, 0, stream>>>(yc, ln_g, ln_b, y1);
        dim3 gu(C4 / BN, DHW / BM);
        gemm_up<<<gu, 256, 0, stream>>>(y1, w1t, b1, y2);
        grn_stats<<<DHW / 128, 256, 0, stream>>>(y2, partial);
        grn_reduce<<<C4, 256, 0, stream>>>(partial, gx2);
        grn_snx<<<1, 256, 0, stream>>>(gx2, gg, snx);
        wscale<<<(Cn * C4 + 255) / 256, 256, 0, stream>>>(w2, snx, w2s);
        dim3 gd(Cn / BN, DHW / BM);
        gemm_down<<<gd, 256, 0, stream>>>(y2, w2s, beff, xb, outb);
    }
}